// Round 6
// baseline (6463.809 us; speedup 1.0000x reference)
//
#include <hip/hip_runtime.h>
#include <math.h>

#define BB 8192
#define TT 60
#define NU 100
#define NI 7

typedef float v2f __attribute__((ext_vector_type(2)));
typedef float v4f __attribute__((ext_vector_type(4)));

// ROUND 6: R5 (LDS weights, 4 trials/wave, 16/block) + rotated loop.
// R5 post-mortem: VALU floor ~105us (pk_fma is HALF-rate: 4cyc/wave64),
// wall 336us at VALUBusy 51% -> stall-bound. The serial z-tail (DPP chain
// + expf + sigmoid + lick state, ~500cyc) sat between publish(t) and
// MACs(t+1) on the critical path, with only 2 waves/SIMD to cover it.
// Fix: software-pipeline — body(t) = [DS reads + 400 FMAs(t)] || [ZED(t-1)
// + stores(t-1)] -> combine/update(t) -> publish. Tail hides under FMA
// issue. Stores are select-based (one guard branch) to keep the MAC+ZED
// region one schedulable block. Only cross-iter dep: publish -> y-reads.
// Weight path unchanged from R5 (proven): wtX/wtY in LDS, per-iter asm
// launder of wofs so LICM can't hoist the 100 ds_reads into registers.

#define FOR25(M) M(0) M(1) M(2) M(3) M(4) M(5) M(6) M(7) M(8) M(9) \
  M(10) M(11) M(12) M(13) M(14) M(15) M(16) M(17) M(18) M(19) \
  M(20) M(21) M(22) M(23) M(24)

#define RL(v,l) __int_as_float(__builtin_amdgcn_readlane(__float_as_int(v), l))

#define DPPADD(ctrl, rmask) { \
  const int _t = __builtin_amdgcn_update_dpp(0, __float_as_int(part), (ctrl), (rmask), 0xf, false); \
  part += __int_as_float(_t); }

#define TRIAL_SETUP(s) \
  const int  trial##s  = tbase + s; \
  const int  stim##s   = stim_idx[trial##s]; \
  const bool isrew##s  = (stim##s == rew_idx[trial##s]); \
  const bool instrb##s = (instr_in[trial##s] > 0); \
  const v2f  wis##s = { fabsf(W_in_raw[ua * NI + stim##s]), fabsf(W_in_raw[(ua+1) * NI + stim##s]) }; \
  v2f  yy##s = ((const v2f*)(y0 + trial##s * NU))[la]; \
  bool licked##s = false, fired##s = false; \
  int  lickt##s = TT + 1; \
  const float* nbase##s = noise + trial##s * (TT * NU); \
  v2f  en##s = ((const v2f*)nbase##s)[la]; \
  bool ia##s = false, u4##s = false, u5##s = false; \
  float z##s = 0.0f;

#define PUBLISH(s) ((v2f*)&lds_y[wid * 4 + s][0])[la] = yy##s;

#define PREF(s) const v2f e##s = en##s; \
  en##s = ((const v2f*)(nbase##s + tn * NU))[la];

#define DECLACC(s) v2f aX0_##s = {0,0}, aX1_##s = {0,0}, aY0_##s = {0,0}, aY1_##s = {0,0};

#define MACQ(s, j2) { \
  const v4f q = Y##s[j2]; \
  aX0_##s += (v2f){q.x, q.y} * wx0; \
  aY0_##s += (v2f){q.x, q.y} * wy0; \
  aX1_##s += (v2f){q.z, q.w} * wx1; \
  aY1_##s += (v2f){q.z, q.w} * wy1; }

// one group: k = 4*j2 .. 4*j2+3; 4 weight b64 shared by all 4 trials
#define MACJ2(j2) { \
  const v2f wx0 = wX[(2*(j2)    ) * 50 + la]; \
  const v2f wx1 = wX[(2*(j2) + 1) * 50 + la]; \
  const v2f wy0 = wY[(2*(j2)    ) * 50 + la]; \
  const v2f wy1 = wY[(2*(j2) + 1) * 50 + la]; \
  MACQ(0, j2) MACQ(1, j2) MACQ(2, j2) MACQ(3, j2) }

// route + base + combine + leaky-relu update for trial s at step t
#define TAILA(s, t, sm, rm) { \
  const bool dl = fired##s || (licked##s && isrew##s); \
  const bool fr = instrb##s && !dl && ((t) == 30); \
  fired##s = fired##s || fr; \
  ia##s = fired##s && ((t) >= 30) && ((t) < 35); \
  const bool ld = licked##s && ((t) > lickt##s) && ((t) < lickt##s + 5); \
  const float ar = (ia##s ? 1.0f : 0.0f) + ((ld && isrew##s) ? 1.0f : 0.0f); \
  const float al = ld ? 1.0f : 0.0f; \
  const v2f base = br + (rm) * wi6 + (sm) * wis##s + ar * wr + al * wl + NS * e##s; \
  const v2f sX = aX0_##s + aX1_##s; \
  const v2f sY = aY0_##s + aY1_##s; \
  const v2f pre  = base + (v2f){ sX.x + sX.y, sY.x + sY.y }; \
  const v2f prer = { fmaxf(pre.x, 0.0f), fmaxf(pre.y, 0.0f) }; \
  yy##s = 0.8f * yy##s + 0.2f * prer; }

// z-reduction + lick state for trial s at step tp (uses ia from ROUTE(tp))
#define ZED(s, tp) { \
  float part = yy##s.x * wo.x + yy##s.y * wo.y; \
  DPPADD(0x111, 0xf) DPPADD(0x112, 0xf) DPPADD(0x114, 0xf) DPPADD(0x118, 0xf) \
  DPPADD(0x142, 0xa) DPPADD(0x143, 0xc) \
  const float xx = RL(part, 63) + bo; \
  z##s = 1.0f / (1.0f + expf(-xx)); \
  const bool inr  = ((tp) >= 20) && ((tp) < 35); \
  const bool trig = inr && !licked##s && (z##s > 0.5f); \
  if (trig) lickt##s = (tp); \
  licked##s = licked##s || trig; \
  u5##s = licked##s && ((tp) >= lickt##s) && ((tp) < lickt##s + 5); \
  u4##s = ia##s || (u5##s && isrew##s); }

// select-based per-step outputs for step tp: ONE guard branch per trial
#define FSTOREP(s, tp) { \
  const float smp = ((tp) >= 10 && (tp) < 15) ? 1.0f : 0.0f; \
  const float rmp = ((tp) >= 20 && (tp) < 35) ? 1.0f : 0.0f; \
  const int bt = trial##s * TT + (tp); \
  if (lane < 11 && lane != 7) { \
    float uv = (lane == stim##s) ? smp : 0.0f; \
    uv = (lane == 4) ? (u4##s ? 1.0f : 0.0f) : uv; \
    uv = (lane == 5) ? (u5##s ? 1.0f : 0.0f) : uv; \
    uv = (lane == 6) ? rmp : uv; \
    const bool isu = lane < NI; \
    float v = isu ? uv \
            : ((lane == 8) ? (isrew##s ? rmp : 0.0f) \
            : ((lane == 9) ? rmp : z##s)); \
    float* p = isu ? (uout + bt * NI + lane) \
             : ((lane == 8) ? (tout + bt) \
             : ((lane == 9) ? (rout + bt) : (zout + bt))); \
    *p = v; } }

__global__ __launch_bounds__(256, 2)
void drr_kernel(const float* __restrict__ y0,
                const float* __restrict__ noise,
                const int*   __restrict__ stim_idx,
                const int*   __restrict__ rew_idx,
                const int*   __restrict__ instr_in,
                const float* __restrict__ W_in_raw,
                const float* __restrict__ W_rec,
                const float* __restrict__ b_rec,
                const float* __restrict__ w_out,
                const float* __restrict__ b_out,
                float* __restrict__ out)
{
    const int tid   = threadIdx.x;
    const int lane  = tid & 63;
    const int wid   = tid >> 6;
    const int tbase = blockIdx.x * 16 + wid * 4;   // 4 trials per wave

    const bool act = (lane < 50);
    const int  la  = act ? lane : 49;
    const int  ua  = 2 * la;

    // transposed-pair weight tiles (40 KB) + per-trial y strips (6.5 KB)
    __shared__ v2f wtX[2500];        // [j][l] = {W[2l][2j],   W[2l][2j+1]}
    __shared__ v2f wtY[2500];        // [j][l] = {W[2l+1][2j], W[2l+1][2j+1]}
    __shared__ v4f lds_y[16][26];    // strip per (wave,trial); 25 v4f used

    // stage weights once per block (writes lane-stride 8B: conflict-free)
    for (int idx = tid; idx < 2500; idx += 256) {
        const int j = idx / 50, l = idx % 50;
        wtX[idx] = *(const v2f*)(W_rec + (2 * l)     * NU + 2 * j);
        wtY[idx] = *(const v2f*)(W_rec + (2 * l + 1) * NU + 2 * j);
    }
    __syncthreads();                 // only barrier in the kernel

    // shared per-unit parameters
    const v2f wi6 = { fabsf(W_in_raw[ua * NI + 6]), fabsf(W_in_raw[(ua+1) * NI + 6]) };
    const v2f wr  = { fabsf(W_in_raw[ua * NI + 4]), fabsf(W_in_raw[(ua+1) * NI + 4]) };
    const v2f wl  = { fabsf(W_in_raw[ua * NI + 5]), fabsf(W_in_raw[(ua+1) * NI + 5]) };
    const v2f br  = { b_rec[ua], b_rec[ua + 1] };
    const v2f wo  = act ? (v2f){ w_out[ua], w_out[ua + 1] } : (v2f){ 0.0f, 0.0f };
    const float bo = b_out[0];
    const float NS = 0.09486832980505138f;   // 0.15 * sqrt(2*0.2)

    TRIAL_SETUP(0) TRIAL_SETUP(1) TRIAL_SETUP(2) TRIAL_SETUP(3)

    const v4f* Y0 = &lds_y[wid * 4 + 0][0];
    const v4f* Y1 = &lds_y[wid * 4 + 1][0];
    const v4f* Y2 = &lds_y[wid * 4 + 2][0];
    const v4f* Y3 = &lds_y[wid * 4 + 3][0];

    // output section pointers (flat tuple order)
    float* uout  = out;                        // B*T*7
    float* tout  = out  + BB * TT * NI;        // B*T
    float* rout  = tout + BB * TT;             // B*T
    float* lout  = rout + BB * TT;             // B
    float* dout  = lout + BB;                  // B
    float* zout  = dout + BB;                  // B*T
    float* yfout = zout + BB * TT;             // B*100

    // publish y(0)
    PUBLISH(0) PUBLISH(1) PUBLISH(2) PUBLISH(3)

    // ---- peeled t = 0: MACs + update + publish (no prior tail) ----
    {
        const int tn = 1;
        PREF(0) PREF(1) PREF(2) PREF(3)

        unsigned wofs = 0;
        asm volatile("" : "+v"(wofs));
        const v2f* wX = (const v2f*)wtX + wofs;
        const v2f* wY = (const v2f*)wtY + wofs;

        DECLACC(0) DECLACC(1) DECLACC(2) DECLACC(3)
        FOR25(MACJ2)

        TAILA(0, 0, 0.0f, 0.0f) TAILA(1, 0, 0.0f, 0.0f)
        TAILA(2, 0, 0.0f, 0.0f) TAILA(3, 0, 0.0f, 0.0f)
        PUBLISH(0) PUBLISH(1) PUBLISH(2) PUBLISH(3)
    }

    // ---- main loop t = 1..59: MACs(t) || tail(t-1) ----
    for (int t = 1; t < TT; ++t) {
        const int tn = (t < TT - 1) ? t + 1 : t;
        PREF(0) PREF(1) PREF(2) PREF(3)

        unsigned wofs = 0;
        asm volatile("" : "+v"(wofs));
        const v2f* wX = (const v2f*)wtX + wofs;
        const v2f* wY = (const v2f*)wtY + wofs;

        DECLACC(0) DECLACC(1) DECLACC(2) DECLACC(3)
        FOR25(MACJ2)     // 100 weight b64 + 100 uniform y b128 + 400 pk_fma

        // finish step t-1 (independent of the accs -> interleaves with FMAs)
        ZED(0, t - 1) ZED(1, t - 1) ZED(2, t - 1) ZED(3, t - 1)
        FSTOREP(0, t - 1) FSTOREP(1, t - 1)
        FSTOREP(2, t - 1) FSTOREP(3, t - 1)

        const float sm = (t >= 10 && t < 15) ? 1.0f : 0.0f;
        const float rm = (t >= 20 && t < 35) ? 1.0f : 0.0f;
        TAILA(0, t, sm, rm) TAILA(1, t, sm, rm)
        TAILA(2, t, sm, rm) TAILA(3, t, sm, rm)

        PUBLISH(0) PUBLISH(1) PUBLISH(2) PUBLISH(3)
    }

    // ---- epilogue: finish step 59 ----
    ZED(0, TT - 1) ZED(1, TT - 1) ZED(2, TT - 1) ZED(3, TT - 1)
    FSTOREP(0, TT - 1) FSTOREP(1, TT - 1)
    FSTOREP(2, TT - 1) FSTOREP(3, TT - 1)

    if (lane == 0) {
        lout[trial0] = licked0 ? 1.0f : 0.0f;
        dout[trial0] = (fired0 || (licked0 && isrew0)) ? 1.0f : 0.0f;
        lout[trial1] = licked1 ? 1.0f : 0.0f;
        dout[trial1] = (fired1 || (licked1 && isrew1)) ? 1.0f : 0.0f;
        lout[trial2] = licked2 ? 1.0f : 0.0f;
        dout[trial2] = (fired2 || (licked2 && isrew2)) ? 1.0f : 0.0f;
        lout[trial3] = licked3 ? 1.0f : 0.0f;
        dout[trial3] = (fired3 || (licked3 && isrew3)) ? 1.0f : 0.0f;
    }
    if (act) {
        ((v2f*)(yfout + trial0 * NU))[la] = yy0;
        ((v2f*)(yfout + trial1 * NU))[la] = yy1;
        ((v2f*)(yfout + trial2 * NU))[la] = yy2;
        ((v2f*)(yfout + trial3 * NU))[la] = yy3;
    }
}

extern "C" void kernel_launch(void* const* d_in, const int* in_sizes, int n_in,
                              void* d_out, int out_size, void* d_ws, size_t ws_size,
                              hipStream_t stream) {
    const float* y0       = (const float*)d_in[0];
    const float* noise    = (const float*)d_in[1];
    const int*   stim     = (const int*)  d_in[2];
    const int*   rew      = (const int*)  d_in[3];
    const int*   instr    = (const int*)  d_in[4];
    const float* W_in_raw = (const float*)d_in[5];
    const float* W_rec    = (const float*)d_in[6];
    const float* b_rec    = (const float*)d_in[7];
    const float* w_out    = (const float*)d_in[8];
    const float* b_out    = (const float*)d_in[9];
    float* out = (float*)d_out;

    drr_kernel<<<BB / 16, 256, 0, stream>>>(y0, noise, stim, rew, instr,
                                            W_in_raw, W_rec, b_rec, w_out, b_out, out);
}

// Round 7
// 565.844 us; speedup vs baseline: 11.4233x; 11.4233x over previous
//
#include <hip/hip_runtime.h>
#include <math.h>

#define BB 8192
#define TT 60
#define NU 100
#define NI 7

typedef float v2f __attribute__((ext_vector_type(2)));
typedef float v4f __attribute__((ext_vector_type(4)));

// ROUND 7: readlane-broadcast MACs; y never touches LDS.
// R5/R6 accounting: R5 was DS-pipe saturated (~1800 DS-cy/wave-step x 8
// waves/CU ~= the 13.4k-cy wall), and 2/3 of that was 100 UNIFORM
// ds_read_b128 y-broadcasts moving only 1.6KB. Fix: broadcast y via
// v_readlane -> SGPR, consume with v_fmac_f32 (same MAC rate as pk_fma:
// 64/2cy vs 128/4cy — R0's real tax was packed-splat movs, which scalar
// fmac avoids since fmaf(w, s_y, acc) legally takes 1 SGPR operand).
// DS now carries ONLY weights: 50 ds_read_b128/wave-step from the block's
// 40KB LDS tile (amortized over 4 trials/wave). No y strips, no publishes,
// no barriers in the loop; the publish->read bubble is gone.
// Spill discipline (R4/R6 lessons): loop body keeps the R5 shape (MACs,
// then tails, no cross-step merging); peak live set = 16 scalar accs.
// Weight-pointer asm launder kept so LICM can't hoist 50 b128 into regs.

#define FOR50(M) M(0) M(1) M(2) M(3) M(4) M(5) M(6) M(7) M(8) M(9) \
  M(10) M(11) M(12) M(13) M(14) M(15) M(16) M(17) M(18) M(19) \
  M(20) M(21) M(22) M(23) M(24) M(25) M(26) M(27) M(28) M(29) \
  M(30) M(31) M(32) M(33) M(34) M(35) M(36) M(37) M(38) M(39) \
  M(40) M(41) M(42) M(43) M(44) M(45) M(46) M(47) M(48) M(49)

#define RL(v,l) __int_as_float(__builtin_amdgcn_readlane(__float_as_int(v), l))

#define DPPADD(ctrl, rmask) { \
  const int _t = __builtin_amdgcn_update_dpp(0, __float_as_int(part), (ctrl), (rmask), 0xf, false); \
  part += __int_as_float(_t); }

#define TRIAL_SETUP(s) \
  const int  trial##s  = tbase + s; \
  const int  stim##s   = stim_idx[trial##s]; \
  const bool isrew##s  = (stim##s == rew_idx[trial##s]); \
  const bool instrb##s = (instr_in[trial##s] > 0); \
  const v2f  wis##s = { fabsf(W_in_raw[ua * NI + stim##s]), fabsf(W_in_raw[(ua+1) * NI + stim##s]) }; \
  v2f  yy##s = ((const v2f*)(y0 + trial##s * NU))[la]; \
  bool licked##s = false, fired##s = false; \
  int  lickt##s = TT + 1; \
  const float* nbase##s = noise + trial##s * (TT * NU); \
  v2f  en##s = ((const v2f*)nbase##s)[la];

#define PREF(s) const v2f e##s = en##s; \
  en##s = ((const v2f*)(nbase##s + tn * NU))[la];

// 4 accumulator chains per trial: (unit A/B) x (k-parity even/odd).
// Chain depth 50 x ~4cy fmac latency = 200cy << issue window: no stall.
#define DECLACC(s) float aAe##s = 0.0f, aAo##s = 0.0f, aBe##s = 0.0f, aBo##s = 0.0f;

// one j (k-pair 2j,2j+1): 1 weight b128 shared by 4 trials,
// 8 readlane (SGPR broadcasts), 16 fmac. w = {W[2l][2j], W[2l][2j+1],
// W[2l+1][2j], W[2l+1][2j+1]}.
#define MACJ(j) { \
  const v4f w = wC[(j) * 50 + la]; \
  const float ya0 = RL(yy0.x, j), yb0 = RL(yy0.y, j); \
  const float ya1 = RL(yy1.x, j), yb1 = RL(yy1.y, j); \
  const float ya2 = RL(yy2.x, j), yb2 = RL(yy2.y, j); \
  const float ya3 = RL(yy3.x, j), yb3 = RL(yy3.y, j); \
  aAe0 = fmaf(w.x, ya0, aAe0); aAo0 = fmaf(w.y, yb0, aAo0); \
  aBe0 = fmaf(w.z, ya0, aBe0); aBo0 = fmaf(w.w, yb0, aBo0); \
  aAe1 = fmaf(w.x, ya1, aAe1); aAo1 = fmaf(w.y, yb1, aAo1); \
  aBe1 = fmaf(w.z, ya1, aBe1); aBo1 = fmaf(w.w, yb1, aBo1); \
  aAe2 = fmaf(w.x, ya2, aAe2); aAo2 = fmaf(w.y, yb2, aAo2); \
  aBe2 = fmaf(w.z, ya2, aBe2); aBo2 = fmaf(w.w, yb2, aBo2); \
  aAe3 = fmaf(w.x, ya3, aAe3); aAo3 = fmaf(w.y, yb3, aAo3); \
  aBe3 = fmaf(w.z, ya3, aBe3); aBo3 = fmaf(w.w, yb3, aBo3); }

// route + base + combine + leaky-relu update for trial s at step t
#define TAILA(s, t, sm, rm) { \
  const bool dl = fired##s || (licked##s && isrew##s); \
  const bool fr = instrb##s && !dl && ((t) == 30); \
  fired##s = fired##s || fr; \
  ia##s = fired##s && ((t) >= 30) && ((t) < 35); \
  const bool ld = licked##s && ((t) > lickt##s) && ((t) < lickt##s + 5); \
  const float ar = (ia##s ? 1.0f : 0.0f) + ((ld && isrew##s) ? 1.0f : 0.0f); \
  const float al = ld ? 1.0f : 0.0f; \
  const v2f base = br + (rm) * wi6 + (sm) * wis##s + ar * wr + al * wl + NS * e##s; \
  const v2f pre  = base + (v2f){ aAe##s + aAo##s, aBe##s + aBo##s }; \
  const v2f prer = { fmaxf(pre.x, 0.0f), fmaxf(pre.y, 0.0f) }; \
  yy##s = 0.8f * yy##s + 0.2f * prer; }

// z-reduction + lick state for trial s at step t
#define ZED(s, t) { \
  float part = yy##s.x * wo.x + yy##s.y * wo.y; \
  DPPADD(0x111, 0xf) DPPADD(0x112, 0xf) DPPADD(0x114, 0xf) DPPADD(0x118, 0xf) \
  DPPADD(0x142, 0xa) DPPADD(0x143, 0xc) \
  const float xx = RL(part, 63) + bo; \
  z##s = 1.0f / (1.0f + expf(-xx)); \
  const bool inr  = ((t) >= 20) && ((t) < 35); \
  const bool trig = inr && !licked##s && (z##s > 0.5f); \
  if (trig) lickt##s = (t); \
  licked##s = licked##s || trig; \
  u5##s = licked##s && ((t) >= lickt##s) && ((t) < lickt##s + 5); \
  u4##s = ia##s || (u5##s && isrew##s); }

#define FSTORE(s, t, sm, rm) { \
  const int bt = trial##s * TT + (t); \
  if (lane < NI) { \
    float uv = 0.0f; \
    if (lane == stim##s) uv = (sm); \
    if (lane == 4) uv = u4##s ? 1.0f : 0.0f; \
    if (lane == 5) uv = u5##s ? 1.0f : 0.0f; \
    if (lane == 6) uv = (rm); \
    uout[bt * NI + lane] = uv; \
  } else if (lane == 8) { tout[bt] = isrew##s ? (rm) : 0.0f; } \
  else if (lane == 9)   { rout[bt] = (rm); } \
  else if (lane == 10)  { zout[bt] = z##s; } }

__global__ __launch_bounds__(256, 2)
void drr_kernel(const float* __restrict__ y0,
                const float* __restrict__ noise,
                const int*   __restrict__ stim_idx,
                const int*   __restrict__ rew_idx,
                const int*   __restrict__ instr_in,
                const float* __restrict__ W_in_raw,
                const float* __restrict__ W_rec,
                const float* __restrict__ b_rec,
                const float* __restrict__ w_out,
                const float* __restrict__ b_out,
                float* __restrict__ out)
{
    const int tid   = threadIdx.x;
    const int lane  = tid & 63;
    const int wid   = tid >> 6;
    const int tbase = blockIdx.x * 16 + wid * 4;   // 4 trials per wave

    const bool act = (lane < 50);
    const int  la  = act ? lane : 49;
    const int  ua  = 2 * la;

    // column-quad weight tile (40 KB, the ONLY loop LDS):
    // wtC[j*50+l] = {W[2l][2j], W[2l][2j+1], W[2l+1][2j], W[2l+1][2j+1]}
    __shared__ v4f wtC[2500];

    {   // stage once per block; v2f halves, conflict-free
        v2f* wt2 = (v2f*)wtC;
        for (int idx = tid; idx < 2500; idx += 256) {
            const int j = idx / 50, l = idx % 50;
            wt2[2 * idx]     = *(const v2f*)(W_rec + (2 * l)     * NU + 2 * j);
            wt2[2 * idx + 1] = *(const v2f*)(W_rec + (2 * l + 1) * NU + 2 * j);
        }
    }
    __syncthreads();                 // only barrier in the kernel

    // shared per-unit parameters
    const v2f wi6 = { fabsf(W_in_raw[ua * NI + 6]), fabsf(W_in_raw[(ua+1) * NI + 6]) };
    const v2f wr  = { fabsf(W_in_raw[ua * NI + 4]), fabsf(W_in_raw[(ua+1) * NI + 4]) };
    const v2f wl  = { fabsf(W_in_raw[ua * NI + 5]), fabsf(W_in_raw[(ua+1) * NI + 5]) };
    const v2f br  = { b_rec[ua], b_rec[ua + 1] };
    const v2f wo  = act ? (v2f){ w_out[ua], w_out[ua + 1] } : (v2f){ 0.0f, 0.0f };
    const float bo = b_out[0];
    const float NS = 0.09486832980505138f;   // 0.15 * sqrt(2*0.2)

    TRIAL_SETUP(0) TRIAL_SETUP(1) TRIAL_SETUP(2) TRIAL_SETUP(3)

    // output section pointers (flat tuple order)
    float* uout  = out;                        // B*T*7
    float* tout  = out  + BB * TT * NI;        // B*T
    float* rout  = tout + BB * TT;             // B*T
    float* lout  = rout + BB * TT;             // B
    float* dout  = lout + BB;                  // B
    float* zout  = dout + BB;                  // B*T
    float* yfout = zout + BB * TT;             // B*100

    for (int t = 0; t < TT; ++t) {
        const int tn = (t < TT - 1) ? t + 1 : t;
        PREF(0) PREF(1) PREF(2) PREF(3)

        // opaque zero offset per iteration: weight addresses stay
        // loop-variant -> LICM cannot hoist the 50 b128 into registers
        unsigned wofs = 0;
        asm volatile("" : "+v"(wofs));
        const v4f* wC = (const v4f*)wtC + wofs;

        DECLACC(0) DECLACC(1) DECLACC(2) DECLACC(3)

        FOR50(MACJ)      // 50 ds_read_b128 + 400 readlane + 800 fmac

        const float sm = (t >= 10 && t < 15) ? 1.0f : 0.0f;
        const float rm = (t >= 20 && t < 35) ? 1.0f : 0.0f;

        bool ia0, ia1, ia2, ia3;
        float z0, z1, z2, z3;
        bool u40, u41, u42, u43, u50, u51, u52, u53;

        TAILA(0, t, sm, rm) TAILA(1, t, sm, rm)
        TAILA(2, t, sm, rm) TAILA(3, t, sm, rm)

        ZED(0, t) ZED(1, t) ZED(2, t) ZED(3, t)

        FSTORE(0, t, sm, rm) FSTORE(1, t, sm, rm)
        FSTORE(2, t, sm, rm) FSTORE(3, t, sm, rm)
    }

    if (lane == 0) {
        lout[trial0] = licked0 ? 1.0f : 0.0f;
        dout[trial0] = (fired0 || (licked0 && isrew0)) ? 1.0f : 0.0f;
        lout[trial1] = licked1 ? 1.0f : 0.0f;
        dout[trial1] = (fired1 || (licked1 && isrew1)) ? 1.0f : 0.0f;
        lout[trial2] = licked2 ? 1.0f : 0.0f;
        dout[trial2] = (fired2 || (licked2 && isrew2)) ? 1.0f : 0.0f;
        lout[trial3] = licked3 ? 1.0f : 0.0f;
        dout[trial3] = (fired3 || (licked3 && isrew3)) ? 1.0f : 0.0f;
    }
    if (act) {
        ((v2f*)(yfout + trial0 * NU))[la] = yy0;
        ((v2f*)(yfout + trial1 * NU))[la] = yy1;
        ((v2f*)(yfout + trial2 * NU))[la] = yy2;
        ((v2f*)(yfout + trial3 * NU))[la] = yy3;
    }
}

extern "C" void kernel_launch(void* const* d_in, const int* in_sizes, int n_in,
                              void* d_out, int out_size, void* d_ws, size_t ws_size,
                              hipStream_t stream) {
    const float* y0       = (const float*)d_in[0];
    const float* noise    = (const float*)d_in[1];
    const int*   stim     = (const int*)  d_in[2];
    const int*   rew      = (const int*)  d_in[3];
    const int*   instr    = (const int*)  d_in[4];
    const float* W_in_raw = (const float*)d_in[5];
    const float* W_rec    = (const float*)d_in[6];
    const float* b_rec    = (const float*)d_in[7];
    const float* w_out    = (const float*)d_in[8];
    const float* b_out    = (const float*)d_in[9];
    float* out = (float*)d_out;

    drr_kernel<<<BB / 16, 256, 0, stream>>>(y0, noise, stim, rew, instr,
                                            W_in_raw, W_rec, b_rec, w_out, b_out, out);
}